// Round 20
// baseline (89.624 us; speedup 1.0000x reference)
//
#include <hip/hip_runtime.h>

typedef unsigned short u16;
typedef __bf16 b16;
typedef b16 b16x8 __attribute__((ext_vector_type(8)));
typedef float f32x4 __attribute__((ext_vector_type(4)));
typedef u16 u16x4 __attribute__((ext_vector_type(4)));
typedef u16 u16x8 __attribute__((ext_vector_type(8)));
typedef float f4 __attribute__((ext_vector_type(4)));

#define NH 8
#define SEQ 4096
#define DM 512
#define HDIM 64
#define GM 8192      // B*S
#define GK 512       // D
#define GN 1536      // 3*D

// Q pre-scale: (1/sqrt(64)) * log2(e)  -> softmax done in exp2 domain
#define QSCALE 0.18033688011112042f
// fixed softmax bias (log2 units): upper bound on max score; p = exp2(s - SMBIAS)
#define SMBIAS 14.0f

__device__ __forceinline__ u16 f2bf(float f) {
  b16 h = (b16)f;
  return __builtin_bit_cast(u16, h);
}

__device__ __forceinline__ float bf2f(u16 u) {
  return __builtin_bit_cast(float, ((unsigned)u) << 16);
}

__device__ __forceinline__ void gl16(const u16* g, u16* l) {
  __builtin_amdgcn_global_load_lds((const __attribute__((address_space(1))) void*)g,
                                   (__attribute__((address_space(3))) void*)l, 16, 0, 0);
}

// ---------------- fused conversions: inputs f32->bf16 and W f32->bf16 transposed -----
__global__ __launch_bounds__(256) void cvt_fused(const float* __restrict__ x,
                                                 u16* __restrict__ y,
                                                 const float* __restrict__ w,
                                                 u16* __restrict__ wt) {
  __shared__ float tile[32][33];
  int bid = blockIdx.x;
  int t = threadIdx.x;
  if (bid < 2048) {
    int i = (bid * 256 + t) * 8;
    f4 a = *(const f4*)(x + i);
    f4 b = *(const f4*)(x + i + 4);
    u16x8 o;
    o[0] = f2bf(a[0]); o[1] = f2bf(a[1]); o[2] = f2bf(a[2]); o[3] = f2bf(a[3]);
    o[4] = f2bf(b[0]); o[5] = f2bf(b[1]); o[6] = f2bf(b[2]); o[7] = f2bf(b[3]);
    *(u16x8*)(y + i) = o;
  } else {
    int q = bid - 2048;                 // 768 blocks
    int n0 = (q % 48) * 32;
    int k0 = (q / 48) * 32;
    int tn = t & 31, tk = t >> 5;
#pragma unroll
    for (int p = 0; p < 4; ++p) {
      int k = tk + p * 8;
      tile[k][tn] = w[(k0 + k) * GN + n0 + tn];
    }
    __syncthreads();
    int n_l = t >> 3, kg = (t & 7) * 4;
    u16x4 o;
#pragma unroll
    for (int i2 = 0; i2 < 4; ++i2) o[i2] = f2bf(tile[kg + i2][n_l]);
    *(u16x4*)(wt + (n0 + n_l) * GK + k0 + kg) = o;
  }
}

// ---------------- QKV GEMM -> Q (scaled), K, and Vt (B,H,64,S) pi-permuted -----------
// Ring-3 LDS staging, counted vmcnt + RAW s_barrier. Each block's bn maps to exactly
// ONE of Q/K/V (bn>>9 uniform). Epilogue goes through padded LDS for coalesced u16x8
// stores; V blocks write the LDS image [e][pi(m)] so V^T comes out directly.
__global__ __launch_bounds__(256, 3) void qkv_gemm(const u16* __restrict__ A,
                                                   const u16* __restrict__ Wt,
                                                   u16* __restrict__ Q,
                                                   u16* __restrict__ K,
                                                   u16* __restrict__ Vt) {
  __shared__ __align__(16) u16 As[3][4096];
  __shared__ __align__(16) u16 Bs[3][4096];
  int bm = blockIdx.x * 128;
  int bn = blockIdx.y * 128;
  int t = threadIdx.x;
  int lane = t & 63, w = t >> 6;
  int wr = w >> 1, wc = w & 1;
  int l15 = lane & 15, g = lane >> 4;

  f32x4 acc[4][4];
#pragma unroll
  for (int i = 0; i < 4; ++i)
#pragma unroll
    for (int j = 0; j < 4; ++j) {
      acc[i][j][0] = 0.f; acc[i][j][1] = 0.f; acc[i][j][2] = 0.f; acc[i][j][3] = 0.f;
    }

#define GSTAGE(slot, k0) do {                                                   \
    _Pragma("unroll")                                                           \
    for (int p = 0; p < 2; ++p) {                                               \
      int cid = p * 256 + t;                                                    \
      int row = cid >> 2, co = (cid & 3) * 8;                                   \
      gl16(A + (size_t)(bm + row) * GK + (k0) + co, &As[slot][cid * 8]);        \
      gl16(Wt + (size_t)(bn + row) * GK + (k0) + co, &Bs[slot][cid * 8]);       \
    }                                                                           \
  } while (0)

  GSTAGE(0, 0);
  GSTAGE(1, 32);
  int cur = 0;
  for (int kk = 0; kk < 16; ++kk) {
    asm volatile("s_waitcnt vmcnt(4)" ::: "memory");
    __builtin_amdgcn_s_barrier();
    int pk = kk + 2 < 16 ? kk + 2 : 15;
    int slot = cur + 2; if (slot >= 3) slot -= 3;
    GSTAGE(slot, pk * 32);

    b16x8 af[4], bf[4];
#pragma unroll
    for (int mi = 0; mi < 4; ++mi)
      af[mi] = *(const b16x8*)(&As[cur][(wr * 64 + mi * 16 + l15) * 32 + g * 8]);
#pragma unroll
    for (int ni = 0; ni < 4; ++ni)
      bf[ni] = *(const b16x8*)(&Bs[cur][(wc * 64 + ni * 16 + l15) * 32 + g * 8]);
    __builtin_amdgcn_s_setprio(1);
#pragma unroll
    for (int mi = 0; mi < 4; ++mi)
#pragma unroll
      for (int ni = 0; ni < 4; ++ni)
        acc[mi][ni] = __builtin_amdgcn_mfma_f32_16x16x32_bf16(af[mi], bf[ni], acc[mi][ni], 0, 0, 0);
    __builtin_amdgcn_s_setprio(0);
    cur = (cur == 2) ? 0 : cur + 1;
  }

  // ---- epilogue through LDS (As/Bs dead). which is BLOCK-uniform. ----
  __syncthreads();
  u16* eps = As[0];                 // 128 x 132 u16 = 33792 B
  const int LDE = 132;
  int which = bn >> 9;
  int h0 = (bn & 511) >> 6;

  if (which < 2) {
    float scale = (which == 0) ? QSCALE : 1.0f;
    // LDS image [m][e]
#pragma unroll
    for (int mi = 0; mi < 4; ++mi)
#pragma unroll
      for (int ni = 0; ni < 4; ++ni) {
        int e_l = wc * 64 + ni * 16 + l15;
#pragma unroll
        for (int r = 0; r < 4; ++r) {
          int m = wr * 64 + mi * 16 + g * 4 + r;
          eps[m * LDE + e_l] = f2bf(acc[mi][ni][r] * scale);
        }
      }
    __syncthreads();
    u16* dst = (which == 0) ? Q : K;
#pragma unroll
    for (int pass = 0; pass < 8; ++pass) {
      int hh = pass & 1;
      int mrow = (pass >> 1) * 32 + (t >> 3);
      int chunk = t & 7;
      u16x8 v = *(const u16x8*)(eps + mrow * LDE + hh * 64 + chunk * 8);
      int mg = bm + mrow;
      int b = mg >> 12, s = mg & 4095;
      *(u16x8*)(dst + ((size_t)((b * NH + h0 + hh) * SEQ) + s) * HDIM + chunk * 8) = v;
    }
  } else {
    // LDS image [e][pi(m)]: pi within each 32-row group: (c&1,g,r)->g*8+(c&1)*4+r
#pragma unroll
    for (int mi = 0; mi < 4; ++mi)
#pragma unroll
      for (int ni = 0; ni < 4; ++ni) {
        int e_l = wc * 64 + ni * 16 + l15;
#pragma unroll
        for (int r = 0; r < 4; ++r) {
          int m = wr * 64 + mi * 16 + g * 4 + r;
          int pm = (m & 96) | (((m >> 2) & 3) << 3) | (((m >> 4) & 1) << 2) | (m & 3);
          eps[e_l * LDE + pm] = f2bf(acc[mi][ni][r]);
        }
      }
    __syncthreads();
#pragma unroll
    for (int pass = 0; pass < 8; ++pass) {
      int rowj = pass * 16 + (t >> 4);          // e-index: (h_half<<6)|dd
      int chunk = t & 15;
      u16x8 v = *(const u16x8*)(eps + rowj * LDE + chunk * 8);
      int dd = rowj & 63, h = h0 + (rowj >> 6);
      int b = bm >> 12, s0 = bm & 4095;
      *(u16x8*)(Vt + ((size_t)((b * NH + h) * HDIM) + dd) * SEQ + s0 + chunk * 8) = v;
    }
  }
}

// ---------------- uniform-length flash attention: sequential pair + kv-split ---------
// Block = (pair p, role): processes q-tile p and q-tile 63-p SEQUENTIALLY (no register
// doubling), each with HALF its kv range (role 0: first halves; role 1: second halves).
// Every block is exactly 32-33 tiles -> all 4 blocks/CU stay resident (no work-decay
// drain). FIXED-BIAS softmax => halves exactly additive. Role 0 writes unnormalized
// f32 O + l0; role 1 writes bf16 Opart + l1; normalize merges. Swapped QK^T, in-reg P,
// K ring-2 + V ring-3, one barrier + vmcnt(0) per tile (R15 pipeline).
__global__ __launch_bounds__(256, 4) void attn(const u16* __restrict__ Q,
                                               const u16* __restrict__ Kv,
                                               const u16* __restrict__ Vtg,
                                               float* __restrict__ out,
                                               u16* __restrict__ Opart,
                                               float* __restrict__ l0,
                                               float* __restrict__ l1) {
  int id = blockIdx.x;
  int bh = id & 15;
  int idx = id >> 4;           // 0..63
  int p = idx >> 1, role = idx & 1;
  int b = bh >> 3, h = bh & 7;
  const u16* Qb = Q + (size_t)bh * SEQ * HDIM;
  const u16* Kb = Kv + (size_t)bh * SEQ * HDIM;
  const u16* Vb = Vtg + (size_t)bh * HDIM * SEQ;   // [64][4096] pi-permuted
  int t = threadIdx.x, lane = t & 63, w = t >> 6;
  int l15 = lane & 15, g = lane >> 4;

  __shared__ __align__(16) u16 Ks[2][4096];
  __shared__ __align__(16) u16 Vs[3][4096];

  int rsub = lane >> 3, cp = lane & 7;
  int ch = cp ^ rsub;
  int xorp = (l15 & 7) << 3;

  // segment tables: seg0 = q-tile p, seg1 = q-tile 63-p
  int hA = (p + 2) >> 1;           // ceil((p+1)/2)
  int hB = (64 - p) >> 1;          // floor((64-p)/2)
  int qts[2], tss[2], tes[2];
  qts[0] = p;      tss[0] = role ? hA : 0; tes[0] = role ? p : hA - 1;
  qts[1] = 63 - p; tss[1] = role ? hB : 0; tes[1] = role ? 63 - p : hB - 1;

  b16x8 vone;
#pragma unroll
  for (int ii = 0; ii < 8; ++ii) vone[ii] = __builtin_bit_cast(b16, (u16)0x3F80);

  f32x4 oaccT[4], lacc;
  b16x8 qf[2];
  b16x8 ptp[2];
  int qw;

#define STAGE2(kslot, vslot, jj) do {                                           \
    _Pragma("unroll")                                                           \
    for (int pp2 = 0; pp2 < 2; ++pp2) {                                         \
      int row = (w * 2 + pp2) * 8 + rsub;                                       \
      gl16(Kb + (size_t)((jj) + row) * HDIM + ch * 8, &Ks[kslot][(w * 2 + pp2) * 512]); \
      gl16(Vb + (size_t)row * SEQ + (jj) + ch * 8, &Vs[vslot][(w * 2 + pp2) * 512]);   \
    }                                                                           \
  } while (0)

  // swapped QK^T: st[c][r] = S[kv = c*16+g*4+r][q = l15]  (C-init = -SMBIAS)
#define QKT(st, kslot) do {                                                     \
    _Pragma("unroll")                                                           \
    for (int c = 0; c < 4; ++c) {                                               \
      st[c][0] = -SMBIAS; st[c][1] = -SMBIAS; st[c][2] = -SMBIAS; st[c][3] = -SMBIAS; \
    }                                                                           \
    _Pragma("unroll")                                                           \
    for (int c = 0; c < 4; ++c) {                                               \
      const u16* kr = Ks[kslot] + (c * 16 + l15) * 64;                          \
      b16x8 kf0 = *(const b16x8*)(kr + ((g * 8) ^ xorp));                       \
      b16x8 kf1 = *(const b16x8*)(kr + ((32 + g * 8) ^ xorp));                  \
      st[c] = __builtin_amdgcn_mfma_f32_16x16x32_bf16(kf0, qf[0], st[c], 0, 0, 0); \
      st[c] = __builtin_amdgcn_mfma_f32_16x16x32_bf16(kf1, qf[1], st[c], 0, 0, 0); \
    }                                                                           \
  } while (0)

  // mask + p=exp2(st) -> bf16 packed into ptX[ks] elem (c&1)*4+r  (all in-register)
#define SMREG(st, jj, ptX) do {                                                 \
    if ((jj) + 63 > qw) {                                                       \
      int qq = qw + l15;                                                        \
      _Pragma("unroll")                                                         \
      for (int c = 0; c < 4; ++c)                                               \
        _Pragma("unroll")                                                       \
        for (int r = 0; r < 4; ++r) {                                           \
          int kvg = (jj) + c * 16 + g * 4 + r;                                  \
          if (kvg > qq) st[c][r] = -1e30f;                                      \
        }                                                                       \
    }                                                                           \
    _Pragma("unroll")                                                           \
    for (int c = 0; c < 4; ++c)                                                 \
      _Pragma("unroll")                                                         \
      for (int r = 0; r < 4; ++r)                                               \
        ptX[c >> 1][(c & 1) * 4 + r] = (b16)__builtin_amdgcn_exp2f(st[c][r]);   \
  } while (0)

  // PV for one tile: O^T += V^T . P^T; V frags from Vs[vslot], P from registers
#define PVT(ptX, vslot) do {                                                    \
    const u16* Vc = Vs[vslot];                                                  \
    _Pragma("unroll")                                                           \
    for (int ks = 0; ks < 2; ++ks) {                                            \
      int eoff = (ks * 32 + g * 8);                                             \
      lacc = __builtin_amdgcn_mfma_f32_16x16x32_bf16(vone, ptX[ks], lacc, 0, 0, 0); \
      _Pragma("unroll")                                                         \
      for (int tdd = 0; tdd < 4; ++tdd) {                                       \
        b16x8 vf = *(const b16x8*)(Vc + (tdd * 16 + l15) * 64 + (eoff ^ xorp)); \
        oaccT[tdd] = __builtin_amdgcn_mfma_f32_16x16x32_bf16(vf, ptX[ks], oaccT[tdd], 0, 0, 0); \
      }                                                                         \
    }                                                                           \
  } while (0)

  for (int s = 0; s < 2; ++s) {
    int qt = qts[s], ts = tss[s], te = tes[s];
    qw = qt * 64 + w * 16;
#pragma unroll
    for (int ii = 0; ii < 4; ++ii) {
      oaccT[ii][0] = 0.f; oaccT[ii][1] = 0.f; oaccT[ii][2] = 0.f; oaccT[ii][3] = 0.f;
      lacc[ii] = 0.f;
    }

    if (s == 1) __builtin_amdgcn_s_barrier();   // protect LDS slots across segments

    if (ts <= te) {
#pragma unroll
      for (int ks = 0; ks < 2; ++ks)
        qf[ks] = *(const b16x8*)(Qb + (qw + l15) * HDIM + ks * 32 + g * 8);

      // prologue: land tile ts, prefetch ts+1, compute P(ts) -> ptp
      STAGE2(ts & 1, ts % 3, ts * 64);
      asm volatile("s_waitcnt vmcnt(0)" ::: "memory");
      __builtin_amdgcn_s_barrier();
      if (ts < te) STAGE2((ts + 1) & 1, (ts + 1) % 3, (ts + 1) * 64);
      {
        f32x4 s0[4];
        QKT(s0, ts & 1);
        SMREG(s0, ts * 64, ptp);
      }

      for (int tt = ts; tt <= te; ++tt) {
        asm volatile("s_waitcnt vmcnt(0)" ::: "memory");
        __builtin_amdgcn_s_barrier();

        if (tt + 2 <= te) STAGE2(tt & 1, (tt + 2) % 3, (tt + 2) * 64);

        bool more = (tt < te);
        f32x4 st[4];
        __builtin_amdgcn_s_setprio(1);
        if (more) QKT(st, (tt + 1) & 1);    // QK(t+1), independent of PV(t)
        PVT(ptp, tt % 3);
        __builtin_amdgcn_s_setprio(0);
        if (more) SMREG(st, (tt + 1) * 64, ptp);
      }
    }

    // ---- epilogue: unnormalized partial. lane owns q = qw + l15. ----
    int q = qw + l15;
    size_t rowbase = ((size_t)b * SEQ + q) * DM + h * HDIM;
    if (role == 0) {
      if (g == 0) l0[bh * SEQ + q] = lacc[0];
#pragma unroll
      for (int tdd = 0; tdd < 4; ++tdd)
        *(f4*)(out + rowbase + tdd * 16 + g * 4) = oaccT[tdd];
    } else {
      if (g == 0) l1[bh * SEQ + q] = lacc[0];
#pragma unroll
      for (int tdd = 0; tdd < 4; ++tdd) {
        u16x4 pw;
#pragma unroll
        for (int r = 0; r < 4; ++r) pw[r] = f2bf(oaccT[tdd][r]);
        *(u16x4*)(Opart + rowbase + tdd * 16 + g * 4) = pw;
      }
    }
  }
}

// ---------------- merge partials + normalize ----------------------------------------
__global__ __launch_bounds__(256) void normalize(float* __restrict__ out,
                                                 const u16* __restrict__ Opart,
                                                 const float* __restrict__ l0,
                                                 const float* __restrict__ l1) {
  size_t idx = ((size_t)blockIdx.x * 256 + threadIdx.x) * 8;
  int dall = (int)(idx & 511);
  int s = (int)((idx >> 9) & 4095);
  int b = (int)(idx >> 21);
  int bh = b * NH + (dall >> 6);
  float l = l0[bh * SEQ + s] + l1[bh * SEQ + s];
  float inv = 1.0f / l;
  f4 v0 = *(f4*)(out + idx);
  f4 v1 = *(f4*)(out + idx + 4);
  u16x8 op = *(const u16x8*)(Opart + idx);
#pragma unroll
  for (int jj = 0; jj < 4; ++jj) {
    v0[jj] = (v0[jj] + bf2f(op[jj])) * inv;
    v1[jj] = (v1[jj] + bf2f(op[4 + jj])) * inv;
  }
  *(f4*)(out + idx) = v0;
  *(f4*)(out + idx + 4) = v1;
}

extern "C" void kernel_launch(void* const* d_in, const int* in_sizes, int n_in,
                              void* d_out, int out_size, void* d_ws, size_t ws_size,
                              hipStream_t stream) {
  const float* x = (const float*)d_in[0];       // (2,4096,512) f32
  const float* wq = (const float*)d_in[1];      // (512,1536) f32
  float* out = (float*)d_out;                   // (2,4096,512) f32
  char* ws = (char*)d_ws;

  u16* A  = (u16*)ws;                                   // 8192x512 bf16; dead after gemm
  u16* Wt = (u16*)(ws + 8388608);                       // dead after gemm
  u16* Qw = (u16*)(ws + 8388608 + 1572864);             // (B,H,S,64) bf16
  u16* Kw = Qw + 4194304;
  u16* Vt = Kw + 4194304;                               // (B,H,64,S) bf16, pi-permuted
  u16* Opart = A;                                       // bf16 partial O (8.4 MB, reuses A)
  float* l0 = (float*)(ws + 8388608);                   // reuses Wt region (256 KB)
  float* l1 = (float*)(ws + 8388608 + 262144);          // (256 KB)

  cvt_fused<<<2816, 256, 0, stream>>>(x, A, wq, Wt);
  dim3 gg(64, 12);
  qkv_gemm<<<gg, 256, 0, stream>>>(A, Wt, Qw, Kw, Vt);
  attn<<<1024, 256, 0, stream>>>(Qw, Kw, Vt, out, Opart, l0, l1);
  normalize<<<2048, 256, 0, stream>>>(out, Opart, l0, l1);
}

// Round 21
// 83.223 us; speedup vs baseline: 1.0769x; 1.0769x over previous
//
#include <hip/hip_runtime.h>

typedef unsigned short u16;
typedef __bf16 b16;
typedef b16 b16x8 __attribute__((ext_vector_type(8)));
typedef float f32x4 __attribute__((ext_vector_type(4)));
typedef u16 u16x4 __attribute__((ext_vector_type(4)));
typedef u16 u16x8 __attribute__((ext_vector_type(8)));
typedef float f4 __attribute__((ext_vector_type(4)));

#define NH 8
#define SEQ 4096
#define DM 512
#define HDIM 64
#define GM 8192      // B*S
#define GK 512       // D
#define GN 1536      // 3*D

// Q pre-scale: (1/sqrt(64)) * log2(e)  -> softmax done in exp2 domain
#define QSCALE 0.18033688011112042f
// fixed softmax bias (log2 units): upper bound on max score; p = exp2(s - SMBIAS)
#define SMBIAS 14.0f

__device__ __forceinline__ u16 f2bf(float f) {
  b16 h = (b16)f;
  return __builtin_bit_cast(u16, h);
}

__device__ __forceinline__ void gl16(const u16* g, u16* l) {
  __builtin_amdgcn_global_load_lds((const __attribute__((address_space(1))) void*)g,
                                   (__attribute__((address_space(3))) void*)l, 16, 0, 0);
}

// ---------------- fused conversions: inputs f32->bf16 and W f32->bf16 transposed -----
__global__ __launch_bounds__(256) void cvt_fused(const float* __restrict__ x,
                                                 u16* __restrict__ y,
                                                 const float* __restrict__ w,
                                                 u16* __restrict__ wt) {
  __shared__ float tile[32][33];
  int bid = blockIdx.x;
  int t = threadIdx.x;
  if (bid < 2048) {
    int i = (bid * 256 + t) * 8;
    f4 a = *(const f4*)(x + i);
    f4 b = *(const f4*)(x + i + 4);
    u16x8 o;
    o[0] = f2bf(a[0]); o[1] = f2bf(a[1]); o[2] = f2bf(a[2]); o[3] = f2bf(a[3]);
    o[4] = f2bf(b[0]); o[5] = f2bf(b[1]); o[6] = f2bf(b[2]); o[7] = f2bf(b[3]);
    *(u16x8*)(y + i) = o;
  } else {
    int q = bid - 2048;                 // 768 blocks
    int n0 = (q % 48) * 32;
    int k0 = (q / 48) * 32;
    int tn = t & 31, tk = t >> 5;
#pragma unroll
    for (int p = 0; p < 4; ++p) {
      int k = tk + p * 8;
      tile[k][tn] = w[(k0 + k) * GN + n0 + tn];
    }
    __syncthreads();
    int n_l = t >> 3, kg = (t & 7) * 4;
    u16x4 o;
#pragma unroll
    for (int i2 = 0; i2 < 4; ++i2) o[i2] = f2bf(tile[kg + i2][n_l]);
    *(u16x4*)(wt + (n0 + n_l) * GK + k0 + kg) = o;
  }
}

// ---------------- QKV GEMM -> Q (scaled), K, and Vt (B,H,64,S) pi-permuted -----------
// Ring-3 LDS staging, counted vmcnt + RAW s_barrier. Each block's bn maps to exactly
// ONE of Q/K/V (bn>>9 uniform). Epilogue goes through padded LDS for coalesced u16x8
// stores; V blocks write the LDS image [e][pi(m)] so V^T comes out directly.
__global__ __launch_bounds__(256, 3) void qkv_gemm(const u16* __restrict__ A,
                                                   const u16* __restrict__ Wt,
                                                   u16* __restrict__ Q,
                                                   u16* __restrict__ K,
                                                   u16* __restrict__ Vt) {
  __shared__ __align__(16) u16 As[3][4096];
  __shared__ __align__(16) u16 Bs[3][4096];
  int bm = blockIdx.x * 128;
  int bn = blockIdx.y * 128;
  int t = threadIdx.x;
  int lane = t & 63, w = t >> 6;
  int wr = w >> 1, wc = w & 1;
  int l15 = lane & 15, g = lane >> 4;

  f32x4 acc[4][4];
#pragma unroll
  for (int i = 0; i < 4; ++i)
#pragma unroll
    for (int j = 0; j < 4; ++j) {
      acc[i][j][0] = 0.f; acc[i][j][1] = 0.f; acc[i][j][2] = 0.f; acc[i][j][3] = 0.f;
    }

#define GSTAGE(slot, k0) do {                                                   \
    _Pragma("unroll")                                                           \
    for (int p = 0; p < 2; ++p) {                                               \
      int cid = p * 256 + t;                                                    \
      int row = cid >> 2, co = (cid & 3) * 8;                                   \
      gl16(A + (size_t)(bm + row) * GK + (k0) + co, &As[slot][cid * 8]);        \
      gl16(Wt + (size_t)(bn + row) * GK + (k0) + co, &Bs[slot][cid * 8]);       \
    }                                                                           \
  } while (0)

  GSTAGE(0, 0);
  GSTAGE(1, 32);
  int cur = 0;
  for (int kk = 0; kk < 16; ++kk) {
    asm volatile("s_waitcnt vmcnt(4)" ::: "memory");
    __builtin_amdgcn_s_barrier();
    int pk = kk + 2 < 16 ? kk + 2 : 15;
    int slot = cur + 2; if (slot >= 3) slot -= 3;
    GSTAGE(slot, pk * 32);

    b16x8 af[4], bf[4];
#pragma unroll
    for (int mi = 0; mi < 4; ++mi)
      af[mi] = *(const b16x8*)(&As[cur][(wr * 64 + mi * 16 + l15) * 32 + g * 8]);
#pragma unroll
    for (int ni = 0; ni < 4; ++ni)
      bf[ni] = *(const b16x8*)(&Bs[cur][(wc * 64 + ni * 16 + l15) * 32 + g * 8]);
    __builtin_amdgcn_s_setprio(1);
#pragma unroll
    for (int mi = 0; mi < 4; ++mi)
#pragma unroll
      for (int ni = 0; ni < 4; ++ni)
        acc[mi][ni] = __builtin_amdgcn_mfma_f32_16x16x32_bf16(af[mi], bf[ni], acc[mi][ni], 0, 0, 0);
    __builtin_amdgcn_s_setprio(0);
    cur = (cur == 2) ? 0 : cur + 1;
  }

  // ---- epilogue through LDS (As/Bs dead). which is BLOCK-uniform. ----
  __syncthreads();
  u16* eps = As[0];                 // 128 x 132 u16 = 33792 B
  const int LDE = 132;
  int which = bn >> 9;
  int h0 = (bn & 511) >> 6;

  if (which < 2) {
    float scale = (which == 0) ? QSCALE : 1.0f;
    // LDS image [m][e]
#pragma unroll
    for (int mi = 0; mi < 4; ++mi)
#pragma unroll
      for (int ni = 0; ni < 4; ++ni) {
        int e_l = wc * 64 + ni * 16 + l15;
#pragma unroll
        for (int r = 0; r < 4; ++r) {
          int m = wr * 64 + mi * 16 + g * 4 + r;
          eps[m * LDE + e_l] = f2bf(acc[mi][ni][r] * scale);
        }
      }
    __syncthreads();
    u16* dst = (which == 0) ? Q : K;
#pragma unroll
    for (int pass = 0; pass < 8; ++pass) {
      int hh = pass & 1;
      int mrow = (pass >> 1) * 32 + (t >> 3);
      int chunk = t & 7;
      u16x8 v = *(const u16x8*)(eps + mrow * LDE + hh * 64 + chunk * 8);
      int mg = bm + mrow;
      int b = mg >> 12, s = mg & 4095;
      *(u16x8*)(dst + ((size_t)((b * NH + h0 + hh) * SEQ) + s) * HDIM + chunk * 8) = v;
    }
  } else {
    // LDS image [e][pi(m)]: pi within each 32-row group: (c&1,g,r)->g*8+(c&1)*4+r
#pragma unroll
    for (int mi = 0; mi < 4; ++mi)
#pragma unroll
      for (int ni = 0; ni < 4; ++ni) {
        int e_l = wc * 64 + ni * 16 + l15;
#pragma unroll
        for (int r = 0; r < 4; ++r) {
          int m = wr * 64 + mi * 16 + g * 4 + r;
          int pm = (m & 96) | (((m >> 2) & 3) << 3) | (((m >> 4) & 1) << 2) | (m & 3);
          eps[e_l * LDE + pm] = f2bf(acc[mi][ni][r]);
        }
      }
    __syncthreads();
#pragma unroll
    for (int pass = 0; pass < 8; ++pass) {
      int rowj = pass * 16 + (t >> 4);          // e-index: (h_half<<6)|dd
      int chunk = t & 15;
      u16x8 v = *(const u16x8*)(eps + rowj * LDE + chunk * 8);
      int dd = rowj & 63, h = h0 + (rowj >> 6);
      int b = bm >> 12, s0 = bm & 4095;
      *(u16x8*)(Vt + ((size_t)((b * NH + h) * HDIM) + dd) * SEQ + s0 + chunk * 8) = v;
    }
  }
}

// ---------------- flash attention, causal, 64 q-rows/block, swapped QK^T -------------
// R15 kernel with ONE change: STAGE issues K,K then V,V and the loop-top wait is
// vmcnt(2) (drains V(t) + K(t+1); V(t+1) stays in flight one extra compute phase).
// vmcnt(0) only on the final iteration. S^T = mfma(K,Q); P in-register; O^T =
// mfma(V^T,P^T). K ring-2 + V ring-3, ONE barrier per tile. FIXED-BIAS softmax;
// row-sum via ones-A MFMA.
__global__ __launch_bounds__(256, 4) void attn(const u16* __restrict__ Q,
                                               const u16* __restrict__ Kv,
                                               const u16* __restrict__ Vtg,
                                               float* __restrict__ out) {
  int id = blockIdx.x;
  int bh = id & 15;
  int i = id >> 4;             // 0..63
  int j = i & 15, pp = i >> 4;
  int qt = (pp == 0) ? 63 - j : (pp == 1) ? j : (pp == 2) ? 47 - j : 16 + j;
  int b = bh >> 3, h = bh & 7;
  const u16* Qb = Q + (size_t)bh * SEQ * HDIM;
  const u16* Kb = Kv + (size_t)bh * SEQ * HDIM;
  const u16* Vb = Vtg + (size_t)bh * HDIM * SEQ;   // [64][4096] pi-permuted
  int t = threadIdx.x, lane = t & 63, w = t >> 6;
  int l15 = lane & 15, g = lane >> 4;
  int qb = qt * 64;
  int qw = qb + w * 16;

  __shared__ __align__(16) u16 Ks[2][4096];
  __shared__ __align__(16) u16 Vs[3][4096];

  int rsub = lane >> 3, cp = lane & 7;
  int ch = cp ^ rsub;
  int xorp = (l15 & 7) << 3;

  b16x8 qf[2];
#pragma unroll
  for (int ks = 0; ks < 2; ++ks)
    qf[ks] = *(const b16x8*)(Qb + (qw + l15) * HDIM + ks * 32 + g * 8);

  b16x8 vone;
#pragma unroll
  for (int ii = 0; ii < 8; ++ii) vone[ii] = __builtin_bit_cast(b16, (u16)0x3F80);

  f32x4 oaccT[4], lacc;
#pragma unroll
  for (int ii = 0; ii < 4; ++ii) {
    oaccT[ii][0] = 0.f; oaccT[ii][1] = 0.f; oaccT[ii][2] = 0.f; oaccT[ii][3] = 0.f;
    lacc[ii] = 0.f;
  }
  b16x8 ptp[2];    // P^T fragments for the current PV tile (in-register)

  // K loads first (both), then V loads: per-wave outstanding order = [K,K,V,V]
#define STAGE2(kslot, vslot, jj) do {                                           \
    _Pragma("unroll")                                                           \
    for (int p = 0; p < 2; ++p) {                                               \
      int row = (w * 2 + p) * 8 + rsub;                                         \
      gl16(Kb + (size_t)((jj) + row) * HDIM + ch * 8, &Ks[kslot][(w * 2 + p) * 512]); \
    }                                                                           \
    _Pragma("unroll")                                                           \
    for (int p = 0; p < 2; ++p) {                                               \
      int row = (w * 2 + p) * 8 + rsub;                                         \
      gl16(Vb + (size_t)row * SEQ + (jj) + ch * 8, &Vs[vslot][(w * 2 + p) * 512]);   \
    }                                                                           \
  } while (0)

  // swapped QK^T: st[c][r] = S[kv = c*16+g*4+r][q = l15]  (C-init = -SMBIAS)
#define QKT(st, kslot) do {                                                     \
    _Pragma("unroll")                                                           \
    for (int c = 0; c < 4; ++c) {                                               \
      st[c][0] = -SMBIAS; st[c][1] = -SMBIAS; st[c][2] = -SMBIAS; st[c][3] = -SMBIAS; \
    }                                                                           \
    _Pragma("unroll")                                                           \
    for (int c = 0; c < 4; ++c) {                                               \
      const u16* kr = Ks[kslot] + (c * 16 + l15) * 64;                          \
      b16x8 kf0 = *(const b16x8*)(kr + ((g * 8) ^ xorp));                       \
      b16x8 kf1 = *(const b16x8*)(kr + ((32 + g * 8) ^ xorp));                  \
      st[c] = __builtin_amdgcn_mfma_f32_16x16x32_bf16(kf0, qf[0], st[c], 0, 0, 0); \
      st[c] = __builtin_amdgcn_mfma_f32_16x16x32_bf16(kf1, qf[1], st[c], 0, 0, 0); \
    }                                                                           \
  } while (0)

  // mask + p=exp2(st) -> bf16 packed into ptX[ks] elem (c&1)*4+r  (all in-register)
#define SMREG(st, jj, ptX) do {                                                 \
    if ((jj) + 63 > qw) {                                                       \
      int qq = qw + l15;                                                        \
      _Pragma("unroll")                                                         \
      for (int c = 0; c < 4; ++c)                                               \
        _Pragma("unroll")                                                       \
        for (int r = 0; r < 4; ++r) {                                           \
          int kvg = (jj) + c * 16 + g * 4 + r;                                  \
          if (kvg > qq) st[c][r] = -1e30f;                                      \
        }                                                                       \
    }                                                                           \
    _Pragma("unroll")                                                           \
    for (int c = 0; c < 4; ++c)                                                 \
      _Pragma("unroll")                                                         \
      for (int r = 0; r < 4; ++r)                                               \
        ptX[c >> 1][(c & 1) * 4 + r] = (b16)__builtin_amdgcn_exp2f(st[c][r]);   \
  } while (0)

  int nt = qt + 1;

  // prologue: land tile 0, prefetch tile 1, compute P(0) in-register
  STAGE2(0, 0, 0);
  asm volatile("s_waitcnt vmcnt(0)" ::: "memory");
  __builtin_amdgcn_s_barrier();
  if (nt > 1) STAGE2(1, 1, 64);
  {
    f32x4 s0[4];
    QKT(s0, 0);
    SMREG(s0, 0, ptp);
  }

  for (int tt = 0; tt < nt; ++tt) {
    // counted wait: V(t) + K(t+1) landed; V(t+1) stays in flight (in-order vmcnt).
    // Final iteration: drain everything.
    if (tt + 1 < nt) {
      asm volatile("s_waitcnt vmcnt(2)" ::: "memory");
    } else {
      asm volatile("s_waitcnt vmcnt(0)" ::: "memory");
    }
    __builtin_amdgcn_s_barrier();

    if (tt + 2 < nt) STAGE2(tt & 1, (tt + 2) % 3, (tt + 2) * 64);

    bool more = (tt + 1 < nt);
    f32x4 st[4];
    __builtin_amdgcn_s_setprio(1);
    if (more) QKT(st, (tt + 1) & 1);        // QK(t+1), independent of PV(t)

    // PV(t): O^T += V^T(t) . P^T(t); V frags from Vs[tt%3], P from registers
    const u16* Vc = Vs[tt % 3];
#pragma unroll
    for (int ks = 0; ks < 2; ++ks) {
      int eoff = (ks * 32 + g * 8);
      lacc = __builtin_amdgcn_mfma_f32_16x16x32_bf16(vone, ptp[ks], lacc, 0, 0, 0);
#pragma unroll
      for (int tdd = 0; tdd < 4; ++tdd) {
        b16x8 vf = *(const b16x8*)(Vc + (tdd * 16 + l15) * 64 + (eoff ^ xorp));
        oaccT[tdd] = __builtin_amdgcn_mfma_f32_16x16x32_bf16(vf, ptp[ks], oaccT[tdd], 0, 0, 0);
      }
    }
    __builtin_amdgcn_s_setprio(0);

    if (more) SMREG(st, (tt + 1) * 64, ptp);  // P(t+1) -> registers for next iter
  }

  // ---- epilogue: lane owns q = qw + l15; O[q][d = tdd*16 + g*4 + r] ----
  float inv = 1.0f / lacc[0];               // all 4 rows of lacc are identical
  size_t rowbase = ((size_t)b * SEQ + qw + l15) * DM + h * HDIM;
#pragma unroll
  for (int tdd = 0; tdd < 4; ++tdd)
#pragma unroll
    for (int r = 0; r < 4; ++r)
      out[rowbase + tdd * 16 + g * 4 + r] = oaccT[tdd][r] * inv;
}

extern "C" void kernel_launch(void* const* d_in, const int* in_sizes, int n_in,
                              void* d_out, int out_size, void* d_ws, size_t ws_size,
                              hipStream_t stream) {
  const float* x = (const float*)d_in[0];       // (2,4096,512) f32
  const float* wq = (const float*)d_in[1];      // (512,1536) f32
  float* out = (float*)d_out;                   // (2,4096,512) f32
  char* ws = (char*)d_ws;

  u16* A  = (u16*)ws;                                   // 8192x512 bf16
  u16* Wt = (u16*)(ws + 8388608);
  u16* Qw = (u16*)(ws + 8388608 + 1572864);             // (B,H,S,64) bf16
  u16* Kw = Qw + 4194304;
  u16* Vt = Kw + 4194304;                               // (B,H,64,S) bf16, pi-permuted

  cvt_fused<<<2816, 256, 0, stream>>>(x, A, wq, Wt);
  dim3 gg(64, 12);
  qkv_gemm<<<gg, 256, 0, stream>>>(A, Wt, Qw, Kw, Vt);
  attn<<<1024, 256, 0, stream>>>(Qw, Kw, Vt, out);
}

// Round 22
// 81.701 us; speedup vs baseline: 1.0970x; 1.0186x over previous
//
#include <hip/hip_runtime.h>

typedef unsigned short u16;
typedef __bf16 b16;
typedef b16 b16x8 __attribute__((ext_vector_type(8)));
typedef float f32x4 __attribute__((ext_vector_type(4)));
typedef u16 u16x4 __attribute__((ext_vector_type(4)));
typedef u16 u16x8 __attribute__((ext_vector_type(8)));
typedef float f4 __attribute__((ext_vector_type(4)));

#define NH 8
#define SEQ 4096
#define DM 512
#define HDIM 64
#define GM 8192      // B*S
#define GK 512       // D
#define GN 1536      // 3*D

// Q pre-scale: (1/sqrt(64)) * log2(e)  -> softmax done in exp2 domain
#define QSCALE 0.18033688011112042f
// fixed softmax bias (log2 units): upper bound on max score; p = exp2(s - SMBIAS)
#define SMBIAS 14.0f

__device__ __forceinline__ u16 f2bf(float f) {
  b16 h = (b16)f;
  return __builtin_bit_cast(u16, h);
}

__device__ __forceinline__ void gl16(const u16* g, u16* l) {
  __builtin_amdgcn_global_load_lds((const __attribute__((address_space(1))) void*)g,
                                   (__attribute__((address_space(3))) void*)l, 16, 0, 0);
}

// ---------------- fused conversions: inputs f32->bf16 and W f32->bf16 transposed -----
__global__ __launch_bounds__(256) void cvt_fused(const float* __restrict__ x,
                                                 u16* __restrict__ y,
                                                 const float* __restrict__ w,
                                                 u16* __restrict__ wt) {
  __shared__ float tile[32][33];
  int bid = blockIdx.x;
  int t = threadIdx.x;
  if (bid < 2048) {
    int i = (bid * 256 + t) * 8;
    f4 a = *(const f4*)(x + i);
    f4 b = *(const f4*)(x + i + 4);
    u16x8 o;
    o[0] = f2bf(a[0]); o[1] = f2bf(a[1]); o[2] = f2bf(a[2]); o[3] = f2bf(a[3]);
    o[4] = f2bf(b[0]); o[5] = f2bf(b[1]); o[6] = f2bf(b[2]); o[7] = f2bf(b[3]);
    *(u16x8*)(y + i) = o;
  } else {
    int q = bid - 2048;                 // 768 blocks
    int n0 = (q % 48) * 32;
    int k0 = (q / 48) * 32;
    int tn = t & 31, tk = t >> 5;
#pragma unroll
    for (int p = 0; p < 4; ++p) {
      int k = tk + p * 8;
      tile[k][tn] = w[(k0 + k) * GN + n0 + tn];
    }
    __syncthreads();
    int n_l = t >> 3, kg = (t & 7) * 4;
    u16x4 o;
#pragma unroll
    for (int i2 = 0; i2 < 4; ++i2) o[i2] = f2bf(tile[kg + i2][n_l]);
    *(u16x4*)(wt + (n0 + n_l) * GK + k0 + kg) = o;
  }
}

// ---------------- QKV GEMM -> Q (scaled), K, and Vt (B,H,64,S) pi-permuted -----------
// Ring-3 LDS staging, counted vmcnt + RAW s_barrier. Each block's bn maps to exactly
// ONE of Q/K/V (bn>>9 uniform). Epilogue goes through padded LDS for coalesced u16x8
// stores; V blocks write the LDS image [e][pi(m)] so V^T comes out directly.
__global__ __launch_bounds__(256, 3) void qkv_gemm(const u16* __restrict__ A,
                                                   const u16* __restrict__ Wt,
                                                   u16* __restrict__ Q,
                                                   u16* __restrict__ K,
                                                   u16* __restrict__ Vt) {
  __shared__ __align__(16) u16 As[3][4096];
  __shared__ __align__(16) u16 Bs[3][4096];
  int bm = blockIdx.x * 128;
  int bn = blockIdx.y * 128;
  int t = threadIdx.x;
  int lane = t & 63, w = t >> 6;
  int wr = w >> 1, wc = w & 1;
  int l15 = lane & 15, g = lane >> 4;

  f32x4 acc[4][4];
#pragma unroll
  for (int i = 0; i < 4; ++i)
#pragma unroll
    for (int j = 0; j < 4; ++j) {
      acc[i][j][0] = 0.f; acc[i][j][1] = 0.f; acc[i][j][2] = 0.f; acc[i][j][3] = 0.f;
    }

#define GSTAGE(slot, k0) do {                                                   \
    _Pragma("unroll")                                                           \
    for (int p = 0; p < 2; ++p) {                                               \
      int cid = p * 256 + t;                                                    \
      int row = cid >> 2, co = (cid & 3) * 8;                                   \
      gl16(A + (size_t)(bm + row) * GK + (k0) + co, &As[slot][cid * 8]);        \
      gl16(Wt + (size_t)(bn + row) * GK + (k0) + co, &Bs[slot][cid * 8]);       \
    }                                                                           \
  } while (0)

  GSTAGE(0, 0);
  GSTAGE(1, 32);
  int cur = 0;
  for (int kk = 0; kk < 16; ++kk) {
    asm volatile("s_waitcnt vmcnt(4)" ::: "memory");
    __builtin_amdgcn_s_barrier();
    int pk = kk + 2 < 16 ? kk + 2 : 15;
    int slot = cur + 2; if (slot >= 3) slot -= 3;
    GSTAGE(slot, pk * 32);

    b16x8 af[4], bf[4];
#pragma unroll
    for (int mi = 0; mi < 4; ++mi)
      af[mi] = *(const b16x8*)(&As[cur][(wr * 64 + mi * 16 + l15) * 32 + g * 8]);
#pragma unroll
    for (int ni = 0; ni < 4; ++ni)
      bf[ni] = *(const b16x8*)(&Bs[cur][(wc * 64 + ni * 16 + l15) * 32 + g * 8]);
    __builtin_amdgcn_s_setprio(1);
#pragma unroll
    for (int mi = 0; mi < 4; ++mi)
#pragma unroll
      for (int ni = 0; ni < 4; ++ni)
        acc[mi][ni] = __builtin_amdgcn_mfma_f32_16x16x32_bf16(af[mi], bf[ni], acc[mi][ni], 0, 0, 0);
    __builtin_amdgcn_s_setprio(0);
    cur = (cur == 2) ? 0 : cur + 1;
  }

  // ---- epilogue through LDS (As/Bs dead). which is BLOCK-uniform. ----
  __syncthreads();
  u16* eps = As[0];                 // 128 x 132 u16 = 33792 B
  const int LDE = 132;
  int which = bn >> 9;
  int h0 = (bn & 511) >> 6;

  if (which < 2) {
    float scale = (which == 0) ? QSCALE : 1.0f;
    // LDS image [m][e]
#pragma unroll
    for (int mi = 0; mi < 4; ++mi)
#pragma unroll
      for (int ni = 0; ni < 4; ++ni) {
        int e_l = wc * 64 + ni * 16 + l15;
#pragma unroll
        for (int r = 0; r < 4; ++r) {
          int m = wr * 64 + mi * 16 + g * 4 + r;
          eps[m * LDE + e_l] = f2bf(acc[mi][ni][r] * scale);
        }
      }
    __syncthreads();
    u16* dst = (which == 0) ? Q : K;
#pragma unroll
    for (int pass = 0; pass < 8; ++pass) {
      int hh = pass & 1;
      int mrow = (pass >> 1) * 32 + (t >> 3);
      int chunk = t & 7;
      u16x8 v = *(const u16x8*)(eps + mrow * LDE + hh * 64 + chunk * 8);
      int mg = bm + mrow;
      int b = mg >> 12, s = mg & 4095;
      *(u16x8*)(dst + ((size_t)((b * NH + h0 + hh) * SEQ) + s) * HDIM + chunk * 8) = v;
    }
  } else {
    // LDS image [e][pi(m)]: pi within each 32-row group: (c&1,g,r)->g*8+(c&1)*4+r
#pragma unroll
    for (int mi = 0; mi < 4; ++mi)
#pragma unroll
      for (int ni = 0; ni < 4; ++ni) {
        int e_l = wc * 64 + ni * 16 + l15;
#pragma unroll
        for (int r = 0; r < 4; ++r) {
          int m = wr * 64 + mi * 16 + g * 4 + r;
          int pm = (m & 96) | (((m >> 2) & 3) << 3) | (((m >> 4) & 1) << 2) | (m & 3);
          eps[e_l * LDE + pm] = f2bf(acc[mi][ni][r]);
        }
      }
    __syncthreads();
#pragma unroll
    for (int pass = 0; pass < 8; ++pass) {
      int rowj = pass * 16 + (t >> 4);          // e-index: (h_half<<6)|dd
      int chunk = t & 15;
      u16x8 v = *(const u16x8*)(eps + rowj * LDE + chunk * 8);
      int dd = rowj & 63, h = h0 + (rowj >> 6);
      int b = bm >> 12, s0 = bm & 4095;
      *(u16x8*)(Vt + ((size_t)((b * NH + h) * HDIM) + dd) * SEQ + s0 + chunk * 8) = v;
    }
  }
}

// ---------------- flash attention, causal, 64 q-rows/block, swapped QK^T -------------
// R15 champion with ONE change: s_setprio REMOVED (attn only). Waves within a block
// are lockstep but the 4 co-resident blocks are at independent phases; setprio may
// starve other blocks' staging/VALU and serialize inter-block overlap (m190 analog).
// S^T = mfma(K,Q); P in-register; O^T = mfma(V^T,P^T). K ring-2 + V ring-3, ONE
// barrier + vmcnt(0) per tile. FIXED-BIAS softmax; ones-A MFMA row-sum.
__global__ __launch_bounds__(256, 4) void attn(const u16* __restrict__ Q,
                                               const u16* __restrict__ Kv,
                                               const u16* __restrict__ Vtg,
                                               float* __restrict__ out) {
  int id = blockIdx.x;
  int bh = id & 15;
  int i = id >> 4;             // 0..63
  int j = i & 15, pp = i >> 4;
  int qt = (pp == 0) ? 63 - j : (pp == 1) ? j : (pp == 2) ? 47 - j : 16 + j;
  int b = bh >> 3, h = bh & 7;
  const u16* Qb = Q + (size_t)bh * SEQ * HDIM;
  const u16* Kb = Kv + (size_t)bh * SEQ * HDIM;
  const u16* Vb = Vtg + (size_t)bh * HDIM * SEQ;   // [64][4096] pi-permuted
  int t = threadIdx.x, lane = t & 63, w = t >> 6;
  int l15 = lane & 15, g = lane >> 4;
  int qb = qt * 64;
  int qw = qb + w * 16;

  __shared__ __align__(16) u16 Ks[2][4096];
  __shared__ __align__(16) u16 Vs[3][4096];

  int rsub = lane >> 3, cp = lane & 7;
  int ch = cp ^ rsub;
  int xorp = (l15 & 7) << 3;

  b16x8 qf[2];
#pragma unroll
  for (int ks = 0; ks < 2; ++ks)
    qf[ks] = *(const b16x8*)(Qb + (qw + l15) * HDIM + ks * 32 + g * 8);

  b16x8 vone;
#pragma unroll
  for (int ii = 0; ii < 8; ++ii) vone[ii] = __builtin_bit_cast(b16, (u16)0x3F80);

  f32x4 oaccT[4], lacc;
#pragma unroll
  for (int ii = 0; ii < 4; ++ii) {
    oaccT[ii][0] = 0.f; oaccT[ii][1] = 0.f; oaccT[ii][2] = 0.f; oaccT[ii][3] = 0.f;
    lacc[ii] = 0.f;
  }
  b16x8 ptp[2];    // P^T fragments for the current PV tile (in-register)

#define STAGE2(kslot, vslot, jj) do {                                           \
    _Pragma("unroll")                                                           \
    for (int p = 0; p < 2; ++p) {                                               \
      int row = (w * 2 + p) * 8 + rsub;                                         \
      gl16(Kb + (size_t)((jj) + row) * HDIM + ch * 8, &Ks[kslot][(w * 2 + p) * 512]); \
      gl16(Vb + (size_t)row * SEQ + (jj) + ch * 8, &Vs[vslot][(w * 2 + p) * 512]);   \
    }                                                                           \
  } while (0)

  // swapped QK^T: st[c][r] = S[kv = c*16+g*4+r][q = l15]  (C-init = -SMBIAS)
#define QKT(st, kslot) do {                                                     \
    _Pragma("unroll")                                                           \
    for (int c = 0; c < 4; ++c) {                                               \
      st[c][0] = -SMBIAS; st[c][1] = -SMBIAS; st[c][2] = -SMBIAS; st[c][3] = -SMBIAS; \
    }                                                                           \
    _Pragma("unroll")                                                           \
    for (int c = 0; c < 4; ++c) {                                               \
      const u16* kr = Ks[kslot] + (c * 16 + l15) * 64;                          \
      b16x8 kf0 = *(const b16x8*)(kr + ((g * 8) ^ xorp));                       \
      b16x8 kf1 = *(const b16x8*)(kr + ((32 + g * 8) ^ xorp));                  \
      st[c] = __builtin_amdgcn_mfma_f32_16x16x32_bf16(kf0, qf[0], st[c], 0, 0, 0); \
      st[c] = __builtin_amdgcn_mfma_f32_16x16x32_bf16(kf1, qf[1], st[c], 0, 0, 0); \
    }                                                                           \
  } while (0)

  // mask + p=exp2(st) -> bf16 packed into ptX[ks] elem (c&1)*4+r  (all in-register)
#define SMREG(st, jj, ptX) do {                                                 \
    if ((jj) + 63 > qw) {                                                       \
      int qq = qw + l15;                                                        \
      _Pragma("unroll")                                                         \
      for (int c = 0; c < 4; ++c)                                               \
        _Pragma("unroll")                                                       \
        for (int r = 0; r < 4; ++r) {                                           \
          int kvg = (jj) + c * 16 + g * 4 + r;                                  \
          if (kvg > qq) st[c][r] = -1e30f;                                      \
        }                                                                       \
    }                                                                           \
    _Pragma("unroll")                                                           \
    for (int c = 0; c < 4; ++c)                                                 \
      _Pragma("unroll")                                                         \
      for (int r = 0; r < 4; ++r)                                               \
        ptX[c >> 1][(c & 1) * 4 + r] = (b16)__builtin_amdgcn_exp2f(st[c][r]);   \
  } while (0)

  int nt = qt + 1;

  // prologue: land tile 0, prefetch tile 1, compute P(0) in-register
  STAGE2(0, 0, 0);
  asm volatile("s_waitcnt vmcnt(0)" ::: "memory");
  __builtin_amdgcn_s_barrier();
  if (nt > 1) STAGE2(1, 1, 64);
  {
    f32x4 s0[4];
    QKT(s0, 0);
    SMREG(s0, 0, ptp);
  }

  for (int tt = 0; tt < nt; ++tt) {
    // K(t+1)/V(t+1) landed (per-wave), then block-wide visibility
    asm volatile("s_waitcnt vmcnt(0)" ::: "memory");
    __builtin_amdgcn_s_barrier();

    if (tt + 2 < nt) STAGE2(tt & 1, (tt + 2) % 3, (tt + 2) * 64);

    bool more = (tt + 1 < nt);
    f32x4 st[4];
    if (more) QKT(st, (tt + 1) & 1);        // QK(t+1), independent of PV(t)

    // PV(t): O^T += V^T(t) . P^T(t); V frags from Vs[tt%3], P from registers
    const u16* Vc = Vs[tt % 3];
#pragma unroll
    for (int ks = 0; ks < 2; ++ks) {
      int eoff = (ks * 32 + g * 8);
      lacc = __builtin_amdgcn_mfma_f32_16x16x32_bf16(vone, ptp[ks], lacc, 0, 0, 0);
#pragma unroll
      for (int tdd = 0; tdd < 4; ++tdd) {
        b16x8 vf = *(const b16x8*)(Vc + (tdd * 16 + l15) * 64 + (eoff ^ xorp));
        oaccT[tdd] = __builtin_amdgcn_mfma_f32_16x16x32_bf16(vf, ptp[ks], oaccT[tdd], 0, 0, 0);
      }
    }

    if (more) SMREG(st, (tt + 1) * 64, ptp);  // P(t+1) -> registers for next iter
  }

  // ---- epilogue: lane owns q = qw + l15; O[q][d = tdd*16 + g*4 + r] ----
  float inv = 1.0f / lacc[0];               // all 4 rows of lacc are identical
  size_t rowbase = ((size_t)b * SEQ + qw + l15) * DM + h * HDIM;
#pragma unroll
  for (int tdd = 0; tdd < 4; ++tdd)
#pragma unroll
    for (int r = 0; r < 4; ++r)
      out[rowbase + tdd * 16 + g * 4 + r] = oaccT[tdd][r] * inv;
}

extern "C" void kernel_launch(void* const* d_in, const int* in_sizes, int n_in,
                              void* d_out, int out_size, void* d_ws, size_t ws_size,
                              hipStream_t stream) {
  const float* x = (const float*)d_in[0];       // (2,4096,512) f32
  const float* wq = (const float*)d_in[1];      // (512,1536) f32
  float* out = (float*)d_out;                   // (2,4096,512) f32
  char* ws = (char*)d_ws;

  u16* A  = (u16*)ws;                                   // 8192x512 bf16
  u16* Wt = (u16*)(ws + 8388608);
  u16* Qw = (u16*)(ws + 8388608 + 1572864);             // (B,H,S,64) bf16
  u16* Kw = Qw + 4194304;
  u16* Vt = Kw + 4194304;                               // (B,H,64,S) bf16, pi-permuted

  cvt_fused<<<2816, 256, 0, stream>>>(x, A, wq, Wt);
  dim3 gg(64, 12);
  qkv_gemm<<<gg, 256, 0, stream>>>(A, Wt, Qw, Kw, Vt);
  attn<<<1024, 256, 0, stream>>>(Qw, Kw, Vt, out);
}